// Round 1
// baseline (512.829 us; speedup 1.0000x reference)
//
#include <hip/hip_runtime.h>
#include <math.h>

// (32, 3, 1024, 1024) fp32, 8x8 window max/min pool -> 20*ln(max/(min+eps))
// masked by (max != min), summed, scaled by w*w/(H*W)/B -> scalar.
// One thread per 8x8 window; 256 threads/block = 2 window-rows of one plane.

#define IMG_ROWS 1024
#define IMG_COLS 1024
#define WIN 8
#define NPLANE (32 * 3)

__global__ __launch_bounds__(256) void eme_window_kernel(
    const float* __restrict__ in, float* __restrict__ out) {
    const int blk   = blockIdx.x;       // 0 .. NPLANE*64 - 1
    const int band  = blk & 63;         // 64 bands of 2 window-rows each
    const int plane = blk >> 6;         // b*3 + c
    const int tid   = threadIdx.x;
    const int wrow  = band * 2 + (tid >> 7);  // window row 0..127
    const int wcol  = tid & 127;              // window col 0..127

    const float* base = in + (size_t)plane * IMG_ROWS * IMG_COLS
                           + (size_t)wrow * WIN * IMG_COLS
                           + (size_t)wcol * WIN;

    float mx = -INFINITY;
    float mn =  INFINITY;
#pragma unroll
    for (int r = 0; r < WIN; ++r) {
        const float4* p = (const float4*)(base + (size_t)r * IMG_COLS);
        float4 a = p[0];
        float4 b = p[1];
        mx = fmaxf(mx, fmaxf(fmaxf(a.x, a.y), fmaxf(a.z, a.w)));
        mx = fmaxf(mx, fmaxf(fmaxf(b.x, b.y), fmaxf(b.z, b.w)));
        mn = fminf(mn, fminf(fminf(a.x, a.y), fminf(a.z, a.w)));
        mn = fminf(mn, fminf(fminf(b.x, b.y), fminf(b.z, b.w)));
    }

    float val = 0.0f;
    if (mx - mn != 0.0f) {
        val = 20.0f * logf(mx / (mn + 1e-4f));
    }

    // wave (64-lane) shuffle reduction
#pragma unroll
    for (int off = 32; off > 0; off >>= 1) {
        val += __shfl_down(val, off, 64);
    }

    __shared__ float wsum[4];
    const int lane = tid & 63;
    const int wave = tid >> 6;
    if (lane == 0) wsum[wave] = val;
    __syncthreads();
    if (tid == 0) {
        float s = wsum[0] + wsum[1] + wsum[2] + wsum[3];
        const float scale = (float)(WIN * WIN) /
                            ((float)IMG_ROWS * (float)IMG_COLS) / 32.0f;
        atomicAdd(out, s * scale);
    }
}

extern "C" void kernel_launch(void* const* d_in, const int* in_sizes, int n_in,
                              void* d_out, int out_size, void* d_ws, size_t ws_size,
                              hipStream_t stream) {
    const float* y_pred = (const float*)d_in[0];
    float* out = (float*)d_out;

    // d_out is poisoned to 0xAA before every timed launch — zero it on-stream.
    hipMemsetAsync(out, 0, sizeof(float), stream);

    const int grid = NPLANE * 64;  // 6144 blocks x 256 threads = 1.57M windows
    eme_window_kernel<<<grid, 256, 0, stream>>>(y_pred, out);
}